// Round 4
// baseline (275.173 us; speedup 1.0000x reference)
//
#include <hip/hip_runtime.h>
#include <hip/hip_bf16.h>

// ---------------------------------------------------------------------------
// GCN 2-layer forward, round 4.
// Changes vs round 3:
//  - XCD-partitioned scatter: nodes split into 8 contiguous ranges; scatter
//    block group p (blockIdx&7, round-robin -> XCD p) scans the whole edge
//    list (NT loads) and commits only dst in range p. Slot window per XCD =
//    1.6 MB -> L2-resident -> stores coalesce in L2 instead of dirtying
//    random HBM lines (was ~100 MB random-line traffic at ~1.7 TB/s).
//  - agg128 + gemm2 fused (k_agg_gemm): aggregate 64 nodes' h1 rows into LDS
//    as fp32 (no bf16 round-trip, h1b buffer deleted), then 64x64 GEMM tile
//    from LDS. One less launch, ~25 MB less traffic, better accuracy.
//  - Scatter slot stores are plain (want L2 writeback caching).
// ---------------------------------------------------------------------------

#define GCN_IN   128
#define GCN_H    128
#define GCN_OUT  64
#define CAP      64
#define OVF_CAP  65536
#define SCAT_BLOCKS 1024   // 8 partitions x 128 blocks

__device__ __forceinline__ ushort f2bf(float f) {     // fp32 -> bf16 RNE
    uint b = __float_as_uint(f);
    b = (b + 0x7FFFu + ((b >> 16) & 1u)) >> 16;
    return (ushort)b;
}
__device__ __forceinline__ float bf2f_lo(uint u) { return __uint_as_float(u << 16); }
__device__ __forceinline__ float bf2f_hi(uint u) { return __uint_as_float(u & 0xFFFF0000u); }
__device__ __forceinline__ float bf2f(ushort u) { return __uint_as_float(((uint)u) << 16); }

// ---------------- fused: [0,SCAT) = XCD-partitioned scatter, rest = GEMM1 ---
// GEMM1: C_bf16[M x 128] = A_f32[M x 128] * B_f32[128 x 128]
__global__ __launch_bounds__(256) void k_fused1(
        const int* __restrict__ src, const int* __restrict__ dst,
        int* __restrict__ cnt, int* __restrict__ slot,
        int* __restrict__ ovfcnt, int2* __restrict__ ovf, int E,
        const float* __restrict__ A, const float* __restrict__ B,
        ushort* __restrict__ C, int M, int N) {
    __shared__ float At[32][68];   // At[k][m], pad 68 -> conflict-free b128
    __shared__ float Bs[32][64];
    const int tid = threadIdx.x;

    if (blockIdx.x < SCAT_BLOCKS) {
        // ---- scatter: partition p = blockIdx&7 (round-robin -> XCD p) ----
        const int part = blockIdx.x & 7;
        const int psz  = (N + 7) >> 3;
        const int lo   = part * psz;
        const int hi   = min(lo + psz, N);
        const int bip  = blockIdx.x >> 3;          // 0..127 within partition
        const int stride = (SCAT_BLOCKS >> 3) * 256;
        for (int e = bip * 256 + tid; e < E; e += stride) {
            int d = __builtin_nontemporal_load(dst + e);
            int s = __builtin_nontemporal_load(src + e);
            if (d >= lo && d < hi) {
                int pos = atomicAdd(&cnt[d], 1);
                if (pos < CAP) {
                    slot[(size_t)d * CAP + pos] = s;   // L2-resident window
                } else {
                    int q = atomicAdd(ovfcnt, 1);
                    if (q < OVF_CAP) ovf[q] = make_int2(d, s);
                }
            }
        }
        return;
    }

    // ---- GEMM1 part ----
    const int g = blockIdx.x - SCAT_BLOCKS;
    const int row0 = (g >> 1) * 64;
    const int col0 = (g & 1) * 64;
    const int tx = tid & 15;
    const int ty = tid >> 4;
    float acc[4][4] = {};

    for (int kb = 0; kb < 128; kb += 32) {
        #pragma unroll
        for (int t = 0; t < 2; ++t) {
            int f = tid * 4 + t * 1024;
            int r = f >> 5;
            int k = f & 31;
            float4 v = make_float4(0.f, 0.f, 0.f, 0.f);
            int gr = row0 + r;
            if (gr < M) v = *(const float4*)(A + (size_t)gr * 128 + kb + k);
            At[k + 0][r] = v.x;
            At[k + 1][r] = v.y;
            At[k + 2][r] = v.z;
            At[k + 3][r] = v.w;
        }
        #pragma unroll
        for (int t = 0; t < 2; ++t) {
            int f = tid * 4 + t * 1024;
            int r = f >> 6;
            int c = f & 63;
            *(float4*)&Bs[r][c] = *(const float4*)(B + (size_t)(kb + r) * 128 + col0 + c);
        }
        __syncthreads();
        #pragma unroll 8
        for (int k = 0; k < 32; ++k) {
            float4 a = *(const float4*)&At[k][ty * 4];
            float4 b = *(const float4*)&Bs[k][tx * 4];
            acc[0][0] += a.x * b.x; acc[0][1] += a.x * b.y; acc[0][2] += a.x * b.z; acc[0][3] += a.x * b.w;
            acc[1][0] += a.y * b.x; acc[1][1] += a.y * b.y; acc[1][2] += a.y * b.z; acc[1][3] += a.y * b.w;
            acc[2][0] += a.z * b.x; acc[2][1] += a.z * b.y; acc[2][2] += a.z * b.z; acc[2][3] += a.z * b.w;
            acc[3][0] += a.w * b.x; acc[3][1] += a.w * b.y; acc[3][2] += a.w * b.z; acc[3][3] += a.w * b.w;
        }
        __syncthreads();
    }
    #pragma unroll
    for (int i = 0; i < 4; ++i) {
        int gr = row0 + ty * 4 + i;
        if (gr < M) {
            ushort4 o;
            o.x = f2bf(acc[i][0]); o.y = f2bf(acc[i][1]);
            o.z = f2bf(acc[i][2]); o.w = f2bf(acc[i][3]);
            *(ushort4*)(C + (size_t)gr * 128 + col0 + tx * 4) = o;
        }
    }
}

// ---------------- fused agg(layer1)+relu+GEMM2 ------------------------------
// Block = 64 nodes. Phase A: wave w aggregates nodes w*16..w*16+15 into LDS
// h1s (fp32, relu'd). Phase B: C_bf16[64 x 64] = h1s[64 x 128] * W2[128 x 64].
__global__ __launch_bounds__(256) void k_agg_gemm(
        const ushort* __restrict__ h,        // hb, N x 128 bf16
        const int* __restrict__ cnt,
        const int* __restrict__ slot,
        const float* __restrict__ bias,      // b1
        const int* __restrict__ ovfcnt,
        const int2* __restrict__ ovf,
        const float* __restrict__ W2,        // 128 x 64 f32
        ushort* __restrict__ h2,             // N x 64 bf16
        int n) {
    __shared__ float h1s[64][132];           // [m][k], pad 132 -> <=2-way
    __shared__ float Bs[32][64];
    const int tid  = threadIdx.x;
    const int lane = tid & 63;
    const int w    = tid >> 6;
    const int node0 = blockIdx.x * 64;
    const float bx = bias[2 * lane];
    const float by = bias[2 * lane + 1];
    const int ovn = *ovfcnt;                 // ~always 0

    // ---- phase A ----
    for (int i = 0; i < 16; ++i) {
        int m = w * 16 + i;
        int node = node0 + m;
        if (node >= n) break;
        int deg = cnt[node];
        int degm = min(deg, CAP);
        float isd_i = rsqrtf((float)(deg + 1));
        int idx = slot[(size_t)node * CAP + lane];     // coalesced 256B
        bool valid = lane < degm;
        int sidx = valid ? idx : 0;
        float wl = valid ? rsqrtf((float)(cnt[sidx] + 1)) : 0.f;

        const ushort* hbp = h + 2 * lane;
        float ax = 0.f, ay = 0.f;
        int j = 0;
        for (; j + 4 <= degm; j += 4) {
            int s0 = __shfl(sidx, j);     int s1 = __shfl(sidx, j + 1);
            int s2 = __shfl(sidx, j + 2); int s3 = __shfl(sidx, j + 3);
            float w0 = __shfl(wl, j);     float w1 = __shfl(wl, j + 1);
            float w2 = __shfl(wl, j + 2); float w3 = __shfl(wl, j + 3);
            uint v0 = *(const uint*)(hbp + (size_t)s0 * 128);
            uint v1 = *(const uint*)(hbp + (size_t)s1 * 128);
            uint v2 = *(const uint*)(hbp + (size_t)s2 * 128);
            uint v3 = *(const uint*)(hbp + (size_t)s3 * 128);
            ax += w0 * bf2f_lo(v0) + w1 * bf2f_lo(v1) + w2 * bf2f_lo(v2) + w3 * bf2f_lo(v3);
            ay += w0 * bf2f_hi(v0) + w1 * bf2f_hi(v1) + w2 * bf2f_hi(v2) + w3 * bf2f_hi(v3);
        }
        for (; j < degm; ++j) {
            int s0 = __shfl(sidx, j);
            float w0 = __shfl(wl, j);
            uint v0 = *(const uint*)(hbp + (size_t)s0 * 128);
            ax += w0 * bf2f_lo(v0);
            ay += w0 * bf2f_hi(v0);
        }
        for (int q = 0; q < ovn; ++q) {
            int2 p = ovf[q];
            if (p.x == node) {
                float w0 = rsqrtf((float)(cnt[p.y] + 1));
                uint v0 = *(const uint*)(hbp + (size_t)p.y * 128);
                ax += w0 * bf2f_lo(v0);
                ay += w0 * bf2f_hi(v0);
            }
        }
        uint vs = *(const uint*)(hbp + (size_t)node * 128);  // self-loop
        ax += isd_i * bf2f_lo(vs);
        ay += isd_i * bf2f_hi(vs);
        ax = fmaxf(ax * isd_i + bx, 0.f);
        ay = fmaxf(ay * isd_i + by, 0.f);
        *(float2*)&h1s[m][2 * lane] = make_float2(ax, ay);
    }
    __syncthreads();

    // ---- phase B ----
    const int tx = tid & 15;
    const int ty = tid >> 4;
    float acc[4][4] = {};
    for (int kb = 0; kb < 128; kb += 32) {
        #pragma unroll
        for (int t = 0; t < 2; ++t) {
            int f = tid * 4 + t * 1024;
            int r = f >> 6;
            int c = f & 63;
            *(float4*)&Bs[r][c] = *(const float4*)(W2 + (size_t)(kb + r) * 64 + c);
        }
        __syncthreads();
        #pragma unroll 8
        for (int k = 0; k < 32; ++k) {
            float a0 = h1s[ty * 4 + 0][kb + k];
            float a1 = h1s[ty * 4 + 1][kb + k];
            float a2 = h1s[ty * 4 + 2][kb + k];
            float a3 = h1s[ty * 4 + 3][kb + k];
            float4 b = *(const float4*)&Bs[k][tx * 4];
            acc[0][0] += a0 * b.x; acc[0][1] += a0 * b.y; acc[0][2] += a0 * b.z; acc[0][3] += a0 * b.w;
            acc[1][0] += a1 * b.x; acc[1][1] += a1 * b.y; acc[1][2] += a1 * b.z; acc[1][3] += a1 * b.w;
            acc[2][0] += a2 * b.x; acc[2][1] += a2 * b.y; acc[2][2] += a2 * b.z; acc[2][3] += a2 * b.w;
            acc[3][0] += a3 * b.x; acc[3][1] += a3 * b.y; acc[3][2] += a3 * b.z; acc[3][3] += a3 * b.w;
        }
        __syncthreads();
    }
    #pragma unroll
    for (int i = 0; i < 4; ++i) {
        int gr = node0 + ty * 4 + i;
        if (gr < n) {
            ushort4 o;
            o.x = f2bf(acc[i][0]); o.y = f2bf(acc[i][1]);
            o.z = f2bf(acc[i][2]); o.w = f2bf(acc[i][3]);
            *(ushort4*)(h2 + (size_t)gr * 64 + tx * 4) = o;
        }
    }
}

// ---------------- agg layer 2: F=64, bf16 in, fp32 out, +bias ---------------
__global__ __launch_bounds__(256) void k_agg64(const ushort* __restrict__ h,
                                               const int* __restrict__ cnt,
                                               const int* __restrict__ slot,
                                               const float* __restrict__ bias,
                                               const int* __restrict__ ovfcnt,
                                               const int2* __restrict__ ovf,
                                               float* __restrict__ out, int n) {
    int node = (blockIdx.x * 256 + threadIdx.x) >> 6;
    int lane = threadIdx.x & 63;
    if (node >= n) return;
    int deg = cnt[node];
    int degm = min(deg, CAP);
    float isd_i = rsqrtf((float)(deg + 1));
    int idx = slot[(size_t)node * CAP + lane];
    bool valid = lane < degm;
    int sidx = valid ? idx : 0;
    float wl = valid ? rsqrtf((float)(cnt[sidx] + 1)) : 0.f;

    const ushort* hb = h + lane;
    float acc = 0.f;
    int j = 0;
    for (; j + 4 <= degm; j += 4) {
        int s0 = __shfl(sidx, j);     int s1 = __shfl(sidx, j + 1);
        int s2 = __shfl(sidx, j + 2); int s3 = __shfl(sidx, j + 3);
        float w0 = __shfl(wl, j);     float w1 = __shfl(wl, j + 1);
        float w2 = __shfl(wl, j + 2); float w3 = __shfl(wl, j + 3);
        float v0 = bf2f(hb[(size_t)s0 * 64]);
        float v1 = bf2f(hb[(size_t)s1 * 64]);
        float v2 = bf2f(hb[(size_t)s2 * 64]);
        float v3 = bf2f(hb[(size_t)s3 * 64]);
        acc += w0 * v0 + w1 * v1 + w2 * v2 + w3 * v3;
    }
    for (; j < degm; ++j) {
        int s0 = __shfl(sidx, j);
        float w0 = __shfl(wl, j);
        acc += w0 * bf2f(hb[(size_t)s0 * 64]);
    }
    int ovn = *ovfcnt;
    for (int q = 0; q < ovn; ++q) {
        int2 p = ovf[q];
        if (p.x == node) acc += rsqrtf((float)(cnt[p.y] + 1)) * bf2f(hb[(size_t)p.y * 64]);
    }
    acc += isd_i * bf2f(hb[(size_t)node * 64]);
    out[(size_t)node * 64 + lane] = acc * isd_i + bias[lane];
}

static inline size_t align256(size_t x) { return (x + 255) & ~(size_t)255; }

extern "C" void kernel_launch(void* const* d_in, const int* in_sizes, int n_in,
                              void* d_out, int out_size, void* d_ws, size_t ws_size,
                              hipStream_t stream) {
    const float* x  = (const float*)d_in[0];
    const int*   ei = (const int*)d_in[1];
    const float* W1 = (const float*)d_in[2];
    const float* b1 = (const float*)d_in[3];
    const float* W2 = (const float*)d_in[4];
    const float* b2 = (const float*)d_in[5];
    float* out = (float*)d_out;

    const int N = in_sizes[0] / GCN_IN;   // 50000
    const int E = in_sizes[1] / 2;        // 800000
    const int* src = ei;
    const int* dst = ei + E;

    char* ws = (char*)d_ws;
    size_t o = 0;
    int*    cnt    = (int*)(ws + o);     o += align256((size_t)N * 4);
    int*    ovfcnt = (int*)(ws + o);     o += 256;
    int2*   ovf    = (int2*)(ws + o);    o += align256((size_t)OVF_CAP * 8);
    int*    slot   = (int*)(ws + o);     o += align256((size_t)N * CAP * 4);
    ushort* hb     = (ushort*)(ws + o);  o += align256((size_t)N * GCN_H * 2);
    ushort* h2b    = (ushort*)(ws + o);  o += align256((size_t)N * GCN_OUT * 2);

    // zero cnt + ovfcnt (contiguous)
    hipMemsetAsync(cnt, 0, align256((size_t)N * 4) + 256, stream);

    // fused: XCD-partitioned scatter (blocks 0..1023) || GEMM1
    {
        int gemm_blocks = ((N + 63) / 64) * 2;
        k_fused1<<<SCAT_BLOCKS + gemm_blocks, 256, 0, stream>>>(
            src, dst, cnt, slot, ovfcnt, ovf, E, x, W1, hb, N, N);
    }

    // fused agg(layer1) + GEMM2 -> h2b
    k_agg_gemm<<<(N + 63) / 64, 256, 0, stream>>>(hb, cnt, slot, b1,
                                                  ovfcnt, ovf, W2, h2b, N);

    // final aggregation -> out
    k_agg64<<<(N * 64 + 255) / 256, 256, 0, stream>>>(h2b, cnt, slot, b2,
                                                      ovfcnt, ovf, out, N);
}

// Round 5
// 213.669 us; speedup vs baseline: 1.2878x; 1.2878x over previous
//
#include <hip/hip_runtime.h>
#include <hip/hip_bf16.h>

// ---------------------------------------------------------------------------
// GCN 2-layer forward, round 5.
// Changes vs round 4:
//  - REVERT agg+gemm2 fusion (occupancy collapse 67%->19% made it 112 us).
//    Back to: fused(scatter||gemm1) -> agg128 -> gemm2 -> agg64.
//  - Agg kernels restructured for wide gathers: each lane reads uint4 (16B),
//    so one wave instruction gathers 4 full rows (agg128, 256B rows) or
//    8 rows (agg64, 128B rows) = 1KB/instr, the coalescing sweet spot.
//    Partial sums per quad/oct folded with shfl_xor butterfly. 4-8x fewer
//    gather instructions at same bytes; register-only, high occupancy.
//  - Scatter stays XCD-partitioned (round 4), fused with GEMM1.
// ---------------------------------------------------------------------------

#define GCN_IN   128
#define GCN_H    128
#define GCN_OUT  64
#define CAP      64
#define OVF_CAP  65536
#define SCAT_BLOCKS 1024   // 8 partitions x 128 blocks

__device__ __forceinline__ ushort f2bf(float f) {     // fp32 -> bf16 RNE
    uint b = __float_as_uint(f);
    b = (b + 0x7FFFu + ((b >> 16) & 1u)) >> 16;
    return (ushort)b;
}
__device__ __forceinline__ float bf2f_lo(uint u) { return __uint_as_float(u << 16); }
__device__ __forceinline__ float bf2f_hi(uint u) { return __uint_as_float(u & 0xFFFF0000u); }

// ---------------- fused: [0,SCAT) = XCD-partitioned scatter, rest = GEMM1 ---
// GEMM1: C_bf16[M x 128] = A_f32[M x 128] * B_f32[128 x 128]
__global__ __launch_bounds__(256) void k_fused1(
        const int* __restrict__ src, const int* __restrict__ dst,
        int* __restrict__ cnt, int* __restrict__ slot,
        int* __restrict__ ovfcnt, int2* __restrict__ ovf, int E,
        const float* __restrict__ A, const float* __restrict__ B,
        ushort* __restrict__ C, int M, int N) {
    __shared__ float At[32][68];   // At[k][m], pad 68 -> conflict-free b128
    __shared__ float Bs[32][64];
    const int tid = threadIdx.x;

    if (blockIdx.x < SCAT_BLOCKS) {
        const int part = blockIdx.x & 7;           // round-robin -> XCD part
        const int psz  = (N + 7) >> 3;
        const int lo   = part * psz;
        const int hi   = min(lo + psz, N);
        const int bip  = blockIdx.x >> 3;          // 0..127 within partition
        const int stride = (SCAT_BLOCKS >> 3) * 256;
        for (int e = bip * 256 + tid; e < E; e += stride) {
            int d = __builtin_nontemporal_load(dst + e);
            int s = __builtin_nontemporal_load(src + e);
            if (d >= lo && d < hi) {
                int pos = atomicAdd(&cnt[d], 1);
                if (pos < CAP) {
                    slot[(size_t)d * CAP + pos] = s;   // L2-resident window
                } else {
                    int q = atomicAdd(ovfcnt, 1);
                    if (q < OVF_CAP) ovf[q] = make_int2(d, s);
                }
            }
        }
        return;
    }

    // ---- GEMM1 part ----
    const int g = blockIdx.x - SCAT_BLOCKS;
    const int row0 = (g >> 1) * 64;
    const int col0 = (g & 1) * 64;
    const int tx = tid & 15;
    const int ty = tid >> 4;
    float acc[4][4] = {};

    for (int kb = 0; kb < 128; kb += 32) {
        #pragma unroll
        for (int t = 0; t < 2; ++t) {
            int f = tid * 4 + t * 1024;
            int r = f >> 5;
            int k = f & 31;
            float4 v = make_float4(0.f, 0.f, 0.f, 0.f);
            int gr = row0 + r;
            if (gr < M) v = *(const float4*)(A + (size_t)gr * 128 + kb + k);
            At[k + 0][r] = v.x;
            At[k + 1][r] = v.y;
            At[k + 2][r] = v.z;
            At[k + 3][r] = v.w;
        }
        #pragma unroll
        for (int t = 0; t < 2; ++t) {
            int f = tid * 4 + t * 1024;
            int r = f >> 6;
            int c = f & 63;
            *(float4*)&Bs[r][c] = *(const float4*)(B + (size_t)(kb + r) * 128 + col0 + c);
        }
        __syncthreads();
        #pragma unroll 8
        for (int k = 0; k < 32; ++k) {
            float4 a = *(const float4*)&At[k][ty * 4];
            float4 b = *(const float4*)&Bs[k][tx * 4];
            acc[0][0] += a.x * b.x; acc[0][1] += a.x * b.y; acc[0][2] += a.x * b.z; acc[0][3] += a.x * b.w;
            acc[1][0] += a.y * b.x; acc[1][1] += a.y * b.y; acc[1][2] += a.y * b.z; acc[1][3] += a.y * b.w;
            acc[2][0] += a.z * b.x; acc[2][1] += a.z * b.y; acc[2][2] += a.z * b.z; acc[2][3] += a.z * b.w;
            acc[3][0] += a.w * b.x; acc[3][1] += a.w * b.y; acc[3][2] += a.w * b.z; acc[3][3] += a.w * b.w;
        }
        __syncthreads();
    }
    #pragma unroll
    for (int i = 0; i < 4; ++i) {
        int gr = row0 + ty * 4 + i;
        if (gr < M) {
            ushort4 o;
            o.x = f2bf(acc[i][0]); o.y = f2bf(acc[i][1]);
            o.z = f2bf(acc[i][2]); o.w = f2bf(acc[i][3]);
            *(ushort4*)(C + (size_t)gr * 128 + col0 + tx * 4) = o;
        }
    }
}

// ---------------- GEMM2: C_bf16[M x 64] = A_bf16[M x 128] * B_f32[128 x 64]
__global__ __launch_bounds__(256) void k_gemm2(const ushort* __restrict__ A,
                                               const float* __restrict__ B,
                                               ushort* __restrict__ C, int M) {
    __shared__ float At[32][68];
    __shared__ float Bs[32][64];
    const int tid = threadIdx.x;
    const int row0 = blockIdx.x * 64;
    const int tx = tid & 15;
    const int ty = tid >> 4;
    float acc[4][4] = {};

    for (int kb = 0; kb < 128; kb += 32) {
        #pragma unroll
        for (int t = 0; t < 2; ++t) {
            int f = tid * 4 + t * 1024;
            int r = f >> 5;
            int k = f & 31;
            uint2 v = make_uint2(0u, 0u);    // 4 bf16
            int gr = row0 + r;
            if (gr < M) v = *(const uint2*)(A + (size_t)gr * 128 + kb + k);
            At[k + 0][r] = bf2f_lo(v.x);
            At[k + 1][r] = bf2f_hi(v.x);
            At[k + 2][r] = bf2f_lo(v.y);
            At[k + 3][r] = bf2f_hi(v.y);
        }
        #pragma unroll
        for (int t = 0; t < 2; ++t) {
            int f = tid * 4 + t * 1024;
            int r = f >> 6;
            int c = f & 63;
            *(float4*)&Bs[r][c] = *(const float4*)(B + (size_t)(kb + r) * 64 + c);
        }
        __syncthreads();
        #pragma unroll 8
        for (int k = 0; k < 32; ++k) {
            float4 a = *(const float4*)&At[k][ty * 4];
            float4 b = *(const float4*)&Bs[k][tx * 4];
            acc[0][0] += a.x * b.x; acc[0][1] += a.x * b.y; acc[0][2] += a.x * b.z; acc[0][3] += a.x * b.w;
            acc[1][0] += a.y * b.x; acc[1][1] += a.y * b.y; acc[1][2] += a.y * b.z; acc[1][3] += a.y * b.w;
            acc[2][0] += a.z * b.x; acc[2][1] += a.z * b.y; acc[2][2] += a.z * b.z; acc[2][3] += a.z * b.w;
            acc[3][0] += a.w * b.x; acc[3][1] += a.w * b.y; acc[3][2] += a.w * b.z; acc[3][3] += a.w * b.w;
        }
        __syncthreads();
    }
    #pragma unroll
    for (int i = 0; i < 4; ++i) {
        int gr = row0 + ty * 4 + i;
        if (gr < M) {
            ushort4 o;
            o.x = f2bf(acc[i][0]); o.y = f2bf(acc[i][1]);
            o.z = f2bf(acc[i][2]); o.w = f2bf(acc[i][3]);
            *(ushort4*)(C + (size_t)gr * 64 + tx * 4) = o;
        }
    }
}

// ---------------- agg layer 1: F=128, bf16 in/out, +bias, relu --------------
// One wave per node. Quad q=lane>>4 handles edge j+q; lane holds features
// 8i..8i+7 (i=lane&15) via one uint4 gather -> 4 rows (1KB) per instruction.
// shfl beyond degm returns zeroed sidx/wl (CAP=64 => max src lane 63).
__global__ __launch_bounds__(256) void k_agg128(const ushort* __restrict__ h,
                                                const int* __restrict__ cnt,
                                                const int* __restrict__ slot,
                                                const float* __restrict__ bias,
                                                const int* __restrict__ ovfcnt,
                                                const int2* __restrict__ ovf,
                                                ushort* __restrict__ out, int n) {
    int node = (blockIdx.x * 256 + threadIdx.x) >> 6;
    int lane = threadIdx.x & 63;
    if (node >= n) return;
    int deg = cnt[node];
    int degm = min(deg, CAP);
    float isd_i = rsqrtf((float)(deg + 1));
    int idx = slot[(size_t)node * CAP + lane];        // coalesced 256B
    bool valid = lane < degm;
    int sidx = valid ? idx : 0;
    float wl = valid ? rsqrtf((float)(cnt[sidx] + 1)) : 0.f;

    const int q = lane >> 4;          // 0..3
    const int i = lane & 15;          // 0..15
    const ushort* hp = h + 8 * i;     // feature offset (8 bf16 per lane)

    float acc[8] = {};
    for (int j = 0; j < degm; j += 8) {          // 8 edges per iter, 2 gathers
        int j0 = j + q;                          // <= 59
        int j1 = j + 4 + q;                      // <= 63
        int   s0 = __shfl(sidx, j0);
        int   s1 = __shfl(sidx, j1);
        float w0 = __shfl(wl, j0);
        float w1 = __shfl(wl, j1);
        uint4 v0 = *(const uint4*)(hp + (size_t)s0 * 128);
        uint4 v1 = *(const uint4*)(hp + (size_t)s1 * 128);
        acc[0] += w0 * bf2f_lo(v0.x) + w1 * bf2f_lo(v1.x);
        acc[1] += w0 * bf2f_hi(v0.x) + w1 * bf2f_hi(v1.x);
        acc[2] += w0 * bf2f_lo(v0.y) + w1 * bf2f_lo(v1.y);
        acc[3] += w0 * bf2f_hi(v0.y) + w1 * bf2f_hi(v1.y);
        acc[4] += w0 * bf2f_lo(v0.z) + w1 * bf2f_lo(v1.z);
        acc[5] += w0 * bf2f_hi(v0.z) + w1 * bf2f_hi(v1.z);
        acc[6] += w0 * bf2f_lo(v0.w) + w1 * bf2f_lo(v1.w);
        acc[7] += w0 * bf2f_hi(v0.w) + w1 * bf2f_hi(v1.w);
    }
    int ovn = *ovfcnt;                            // ~always 0
    for (int t = 0; t < ovn; ++t) {
        int2 p = ovf[t];
        if (p.x == node && q == 0) {              // q==0 lanes cover full row
            float w0 = rsqrtf((float)(cnt[p.y] + 1));
            uint4 v0 = *(const uint4*)(hp + (size_t)p.y * 128);
            acc[0] += w0 * bf2f_lo(v0.x); acc[1] += w0 * bf2f_hi(v0.x);
            acc[2] += w0 * bf2f_lo(v0.y); acc[3] += w0 * bf2f_hi(v0.y);
            acc[4] += w0 * bf2f_lo(v0.z); acc[5] += w0 * bf2f_hi(v0.z);
            acc[6] += w0 * bf2f_lo(v0.w); acc[7] += w0 * bf2f_hi(v0.w);
        }
    }
    #pragma unroll
    for (int k = 0; k < 8; ++k) {                 // fold quads
        acc[k] += __shfl_xor(acc[k], 16);
        acc[k] += __shfl_xor(acc[k], 32);
    }
    if (q == 0) {
        uint4 vs = *(const uint4*)(hp + (size_t)node * 128);  // self-loop
        float4 ba = *(const float4*)(bias + 8 * i);
        float4 bb = *(const float4*)(bias + 8 * i + 4);
        float r0 = fmaxf((acc[0] + isd_i * bf2f_lo(vs.x)) * isd_i + ba.x, 0.f);
        float r1 = fmaxf((acc[1] + isd_i * bf2f_hi(vs.x)) * isd_i + ba.y, 0.f);
        float r2 = fmaxf((acc[2] + isd_i * bf2f_lo(vs.y)) * isd_i + ba.z, 0.f);
        float r3 = fmaxf((acc[3] + isd_i * bf2f_hi(vs.y)) * isd_i + ba.w, 0.f);
        float r4 = fmaxf((acc[4] + isd_i * bf2f_lo(vs.z)) * isd_i + bb.x, 0.f);
        float r5 = fmaxf((acc[5] + isd_i * bf2f_hi(vs.z)) * isd_i + bb.y, 0.f);
        float r6 = fmaxf((acc[6] + isd_i * bf2f_lo(vs.w)) * isd_i + bb.z, 0.f);
        float r7 = fmaxf((acc[7] + isd_i * bf2f_hi(vs.w)) * isd_i + bb.w, 0.f);
        uint4 o;
        o.x = (uint)f2bf(r0) | ((uint)f2bf(r1) << 16);
        o.y = (uint)f2bf(r2) | ((uint)f2bf(r3) << 16);
        o.z = (uint)f2bf(r4) | ((uint)f2bf(r5) << 16);
        o.w = (uint)f2bf(r6) | ((uint)f2bf(r7) << 16);
        *(uint4*)(out + (size_t)node * 128 + 8 * i) = o;
    }
}

// ---------------- agg layer 2: F=64, bf16 in, fp32 out, +bias ---------------
// Oct g=lane>>3 handles edge j+g; lane holds features 8i..8i+7 (i=lane&7)
// via one uint4 gather -> 8 rows (1KB) per instruction.
__global__ __launch_bounds__(256) void k_agg64(const ushort* __restrict__ h,
                                               const int* __restrict__ cnt,
                                               const int* __restrict__ slot,
                                               const float* __restrict__ bias,
                                               const int* __restrict__ ovfcnt,
                                               const int2* __restrict__ ovf,
                                               float* __restrict__ out, int n) {
    int node = (blockIdx.x * 256 + threadIdx.x) >> 6;
    int lane = threadIdx.x & 63;
    if (node >= n) return;
    int deg = cnt[node];
    int degm = min(deg, CAP);
    float isd_i = rsqrtf((float)(deg + 1));
    int idx = slot[(size_t)node * CAP + lane];
    bool valid = lane < degm;
    int sidx = valid ? idx : 0;
    float wl = valid ? rsqrtf((float)(cnt[sidx] + 1)) : 0.f;

    const int g = lane >> 3;          // 0..7
    const int i = lane & 7;           // 0..7
    const ushort* hp = h + 8 * i;

    float acc[8] = {};
    for (int j = 0; j < degm; j += 16) {         // 16 edges per iter, 2 gathers
        int j0 = j + g;                          // <= 55
        int j1 = j + 8 + g;                      // <= 63
        int   s0 = __shfl(sidx, j0);
        int   s1 = __shfl(sidx, j1);
        float w0 = __shfl(wl, j0);
        float w1 = __shfl(wl, j1);
        uint4 v0 = *(const uint4*)(hp + (size_t)s0 * 64);
        uint4 v1 = *(const uint4*)(hp + (size_t)s1 * 64);
        acc[0] += w0 * bf2f_lo(v0.x) + w1 * bf2f_lo(v1.x);
        acc[1] += w0 * bf2f_hi(v0.x) + w1 * bf2f_hi(v1.x);
        acc[2] += w0 * bf2f_lo(v0.y) + w1 * bf2f_lo(v1.y);
        acc[3] += w0 * bf2f_hi(v0.y) + w1 * bf2f_hi(v1.y);
        acc[4] += w0 * bf2f_lo(v0.z) + w1 * bf2f_lo(v1.z);
        acc[5] += w0 * bf2f_hi(v0.z) + w1 * bf2f_hi(v1.z);
        acc[6] += w0 * bf2f_lo(v0.w) + w1 * bf2f_lo(v1.w);
        acc[7] += w0 * bf2f_hi(v0.w) + w1 * bf2f_hi(v1.w);
    }
    int ovn = *ovfcnt;
    for (int t = 0; t < ovn; ++t) {
        int2 p = ovf[t];
        if (p.x == node && g == 0) {
            float w0 = rsqrtf((float)(cnt[p.y] + 1));
            uint4 v0 = *(const uint4*)(hp + (size_t)p.y * 64);
            acc[0] += w0 * bf2f_lo(v0.x); acc[1] += w0 * bf2f_hi(v0.x);
            acc[2] += w0 * bf2f_lo(v0.y); acc[3] += w0 * bf2f_hi(v0.y);
            acc[4] += w0 * bf2f_lo(v0.z); acc[5] += w0 * bf2f_hi(v0.z);
            acc[6] += w0 * bf2f_lo(v0.w); acc[7] += w0 * bf2f_hi(v0.w);
        }
    }
    #pragma unroll
    for (int k = 0; k < 8; ++k) {                // fold octs
        acc[k] += __shfl_xor(acc[k], 8);
        acc[k] += __shfl_xor(acc[k], 16);
        acc[k] += __shfl_xor(acc[k], 32);
    }
    if (g == 0) {
        uint4 vs = *(const uint4*)(hp + (size_t)node * 64);   // self-loop
        float4 ba = *(const float4*)(bias + 8 * i);
        float4 bb = *(const float4*)(bias + 8 * i + 4);
        float4 r0, r1;
        r0.x = (acc[0] + isd_i * bf2f_lo(vs.x)) * isd_i + ba.x;
        r0.y = (acc[1] + isd_i * bf2f_hi(vs.x)) * isd_i + ba.y;
        r0.z = (acc[2] + isd_i * bf2f_lo(vs.y)) * isd_i + ba.z;
        r0.w = (acc[3] + isd_i * bf2f_hi(vs.y)) * isd_i + ba.w;
        r1.x = (acc[4] + isd_i * bf2f_lo(vs.z)) * isd_i + bb.x;
        r1.y = (acc[5] + isd_i * bf2f_hi(vs.z)) * isd_i + bb.y;
        r1.z = (acc[6] + isd_i * bf2f_lo(vs.w)) * isd_i + bb.z;
        r1.w = (acc[7] + isd_i * bf2f_hi(vs.w)) * isd_i + bb.w;
        float* op = out + (size_t)node * 64 + 8 * i;
        *(float4*)op = r0;
        *(float4*)(op + 4) = r1;
    }
}

static inline size_t align256(size_t x) { return (x + 255) & ~(size_t)255; }

extern "C" void kernel_launch(void* const* d_in, const int* in_sizes, int n_in,
                              void* d_out, int out_size, void* d_ws, size_t ws_size,
                              hipStream_t stream) {
    const float* x  = (const float*)d_in[0];
    const int*   ei = (const int*)d_in[1];
    const float* W1 = (const float*)d_in[2];
    const float* b1 = (const float*)d_in[3];
    const float* W2 = (const float*)d_in[4];
    const float* b2 = (const float*)d_in[5];
    float* out = (float*)d_out;

    const int N = in_sizes[0] / GCN_IN;   // 50000
    const int E = in_sizes[1] / 2;        // 800000
    const int* src = ei;
    const int* dst = ei + E;

    char* ws = (char*)d_ws;
    size_t o = 0;
    int*    cnt    = (int*)(ws + o);     o += align256((size_t)N * 4);
    int*    ovfcnt = (int*)(ws + o);     o += 256;
    int2*   ovf    = (int2*)(ws + o);    o += align256((size_t)OVF_CAP * 8);
    int*    slot   = (int*)(ws + o);     o += align256((size_t)N * CAP * 4);
    ushort* hb     = (ushort*)(ws + o);  o += align256((size_t)N * GCN_H * 2);
    ushort* h1b    = (ushort*)(ws + o);  o += align256((size_t)N * GCN_H * 2);
    ushort* h2b    = (ushort*)(ws + o);  o += align256((size_t)N * GCN_OUT * 2);

    // zero cnt + ovfcnt (contiguous)
    hipMemsetAsync(cnt, 0, align256((size_t)N * 4) + 256, stream);

    // fused: XCD-partitioned scatter (blocks 0..1023) || GEMM1
    {
        int gemm_blocks = ((N + 63) / 64) * 2;
        k_fused1<<<SCAT_BLOCKS + gemm_blocks, 256, 0, stream>>>(
            src, dst, cnt, slot, ovfcnt, ovf, E, x, W1, hb, N, N);
    }

    // agg layer 1 -> h1b (bf16)
    k_agg128<<<(N * 64 + 255) / 256, 256, 0, stream>>>(hb, cnt, slot, b1,
                                                       ovfcnt, ovf, h1b, N);
    // GEMM2: h1b @ W2 -> h2b (bf16)
    k_gemm2<<<(N + 63) / 64, 256, 0, stream>>>(h1b, W2, h2b, N);

    // agg layer 2 -> out (fp32)
    k_agg64<<<(N * 64 + 255) / 256, 256, 0, stream>>>(h2b, cnt, slot, b2,
                                                      ovfcnt, ovf, out, N);
}